// Round 3
// baseline (593.781 us; speedup 1.0000x reference)
//
#include <hip/hip_runtime.h>

#define BATCH 16
#define NV    20000
#define FIN   64
#define NCOUT 64
#define NK    16
#define TOTROWS (BATCH * NV)

// 768 blocks = 3 blocks/CU at launch_bounds(256,3): ALL blocks co-resident,
// so each XCD's 96 blocks sweep one batch window (5.12 MB) coherently.
// Round-2 lesson: 2048 blocks with ~3 resident/CU left 2/3 of blocks lagging
// a full batch behind -> two live windows -> 2.7x gather over-fetch.
#define NBLOCKS 768

typedef __attribute__((ext_vector_type(2))) float f32x2;

// Single fused pass. One wave per output row (b,v):
//   lane = feature f for {x-row load, neighbor gather-sum} (coalesced),
//   lane = out column c for the matmul (weights in VGPRs),
//   one LDS float4-broadcast round trip transposes [xf | nbs] between views.
// out[c] = sum_f xf[f]*Wx[f][c] + sum_f nbs[f]*(Wn[f][c]/16) + b[c]
__global__ __launch_bounds__(256, 3) void convnet_fused1(
    const float* __restrict__ x,     // (B, V, 64) fp32
    const float* __restrict__ Wx,    // (64, 64)
    const float* __restrict__ Wn,    // (64, 64)
    const float* __restrict__ bias,  // (64)
    const int*   __restrict__ nbr,   // (V, 16), values in [0, V]; 0 = pad
    const float* __restrict__ zrow,  // 64 floats of zeros (in d_ws)
    float*       __restrict__ out)   // (B, V, 64) fp32
{
    __shared__ __align__(16) float sx[4][FIN];
    __shared__ __align__(16) float sn[4][FIN];

    const int lane = threadIdx.x & 63;
    const int wave = threadIdx.x >> 6;

    // Per-lane weight columns as float2 pairs over f -> v_pk_fma_f32.
    // wx2[q] = (Wx[2q][lane], Wx[2q+1][lane]); Wn pre-scaled by 1/16.
    f32x2 wx2[FIN / 2], wn2[FIN / 2];
#pragma unroll
    for (int q = 0; q < FIN / 2; ++q) {
        wx2[q] = (f32x2){Wx[(2 * q) * NCOUT + lane], Wx[(2 * q + 1) * NCOUT + lane]};
        wn2[q] = (f32x2){Wn[(2 * q) * NCOUT + lane] * (1.0f / 16.0f),
                         Wn[(2 * q + 1) * NCOUT + lane] * (1.0f / 16.0f)};
    }
    const float bias_r = bias[lane];

    const int xcd = blockIdx.x & 7;            // round-robin block->XCD
    const int bi  = blockIdx.x >> 3;           // block index within XCD [0,96)
    const int wl  = (bi * blockDim.x + threadIdx.x) >> 6;  // wave in XCD [0,384)
    const int wpx = (NBLOCKS / 8) * (256 / 64);            // 384 waves/XCD
    const int rows_per_xcd = 2 * NV;           // XCD owns batches 2*xcd, 2*xcd+1
    const int base = xcd * rows_per_xcd;

    float* sxw = &sx[wave][0];
    float* snw = &sn[wave][0];

    for (int r = wl; r < rows_per_xcd; r += wpx) {
        const int rowu = __builtin_amdgcn_readfirstlane(base + r);
        const int in_b1 = (r >= NV) ? 1 : 0;
        const int v = r - in_b1 * NV;

        const float* xb    = x + (size_t)(2 * xcd + in_b1) * (NV * FIN);
        const int*   nbrow = nbr + (size_t)v * NK;

        // x row, lane = f (coalesced vector load; also warms L2 for gathers).
        const float xf = x[(size_t)rowu * FIN + lane];

        // Gather-sum of 16 neighbor x-rows, lane = f. Pad (idx==0) handled by
        // a SCALAR pointer select to the zero row: 1 load + 1 v_add per k.
        float g0 = 0.0f, g1 = 0.0f;
#pragma unroll
        for (int k = 0; k < NK; ++k) {
            const int idx = nbrow[k];                          // uniform s_load
            const float* src = idx ? (xb + (size_t)(idx - 1) * FIN) : zrow;
            const float val = src[lane];
            if (k & 1) g1 += val; else g0 += val;
        }
        const float nbs = g0 + g1;

        // Transpose [xf | nbs] through LDS; read back as float4 broadcasts.
        sxw[lane] = xf;
        snw[lane] = nbs;
        __builtin_amdgcn_wave_barrier();  // same-wave LDS ops are in-order

        f32x2 a0 = {bias_r, 0.0f}, a1 = {0.0f, 0.0f};
        f32x2 a2 = {0.0f, 0.0f},  a3 = {0.0f, 0.0f};
        const float4* sx4 = (const float4*)sxw;
        const float4* sn4 = (const float4*)snw;
#pragma unroll
        for (int q = 0; q < FIN / 4; ++q) {
            const float4 xa = sx4[q];
            const float4 na = sn4[q];
            a0 += (f32x2){xa.x, xa.y} * wx2[2 * q + 0];
            a1 += (f32x2){xa.z, xa.w} * wx2[2 * q + 1];
            a2 += (f32x2){na.x, na.y} * wn2[2 * q + 0];
            a3 += (f32x2){na.z, na.w} * wn2[2 * q + 1];
        }
        const f32x2 s = (a0 + a1) + (a2 + a3);
        // Non-temporal store: don't let 82 MB of out evict the gather window.
        __builtin_nontemporal_store(s.x + s.y, &out[(size_t)rowu * NCOUT + lane]);
    }
}

extern "C" void kernel_launch(void* const* d_in, const int* in_sizes, int n_in,
                              void* d_out, int out_size, void* d_ws, size_t ws_size,
                              hipStream_t stream) {
    const float* x    = (const float*)d_in[0];
    const float* Wx   = (const float*)d_in[1];
    const float* Wn   = (const float*)d_in[2];
    const float* bias = (const float*)d_in[3];
    const int*   nbr  = (const int*)d_in[4];
    float* out = (float*)d_out;

    // Zero row for the pad-index pointer select (d_ws is poisoned 0xAA
    // before every launch -> must re-zero every call; memset is capturable).
    float* zrow = (float*)d_ws;
    hipMemsetAsync(zrow, 0, FIN * sizeof(float), stream);

    dim3 grid(NBLOCKS), block(256);
    hipLaunchKernelGGL(convnet_fused1, grid, block, 0, stream,
                       x, Wx, Wn, bias, nbr, zrow, out);
}

// Round 4
// 304.044 us; speedup vs baseline: 1.9529x; 1.9529x over previous
//
#include <hip/hip_runtime.h>
#include <hip/hip_bf16.h>

#define BATCH 16
#define NV    20000
#define FIN   64
#define NCOUT 64
#define NK    16
#define TOTROWS  (BATCH * NV)      // 320000
#define NTILES   (TOTROWS / 16)    // 20000 row-tiles of 16

typedef __attribute__((ext_vector_type(8))) short bf16x8;   // 8 bf16 (4 VGPRs)
typedef __attribute__((ext_vector_type(4))) float f32x4;    // MFMA acc

__device__ __forceinline__ short f2b(float f) {
    __hip_bfloat16 h = __float2bfloat16(f);   // RTNE
    return __builtin_bit_cast(short, h);
}

// ---------------------------------------------------------------------------
// Pass A: one x-sweep, MFMA 16x16x32 bf16.
//   p[row][c]   = x[row]@Wx[:,c] + bias[c]      -> out  (fp32)
//   z[row][c]   = x[row]@(Wn[:,c]/16)           -> ws   (bf16)
// Wave handles a 16-row tile x 128 cols = 8 col-tiles x 2 k-halves = 16 MFMA.
// B-frags (weights) built ONCE into 64 VGPRs -- round-3 lesson: the compiler
// refuses to keep fp32 weight *arrays* resident across a loop (VGPR_Count=84
// with 128 floats "in registers" => it was re-streaming 32 KB/row through L1).
// MFMA frags are hot operands of the loop body; they stay resident.
// ---------------------------------------------------------------------------
__global__ __launch_bounds__(256, 3) void convnet_gemm(
    const float* __restrict__ x,      // (320000, 64)
    const float* __restrict__ Wx,     // (64, 64)
    const float* __restrict__ Wn,     // (64, 64)
    const float* __restrict__ bias,   // (64)
    __hip_bfloat16* __restrict__ z,   // (320000, 64) bf16  [ws]
    float* __restrict__ out)          // (320000, 64) fp32  (gets p)
{
    const int lane = threadIdx.x & 63;
    const int m    = lane & 15;    // row-in-tile (A), col-in-tile (B, C/D)
    const int quad = lane >> 4;    // 0..3

    // B fragments: bf[t][h], t 0..3 = Wx (-> p), t 4..7 = Wn/16 (-> z).
    // Layout (verified m91/gemm_bt): frag[j] = W[k][n], n = lane&15,
    // k = 32*h + quad*8 + j.
    bf16x8 bf[8][2];
#pragma unroll
    for (int t = 0; t < 8; ++t) {
        const float* W = (t < 4) ? Wx : Wn;
        const float scale = (t < 4) ? 1.0f : (1.0f / 16.0f);
        const int c = (t & 3) * 16 + m;
#pragma unroll
        for (int h = 0; h < 2; ++h) {
            bf16x8 fr;
#pragma unroll
            for (int j = 0; j < 8; ++j) {
                const int f = 32 * h + quad * 8 + j;
                fr[j] = f2b(W[f * NCOUT + c] * scale);
            }
            bf[t][h] = fr;
        }
    }
    float bias_q[4];
#pragma unroll
    for (int t = 0; t < 4; ++t) bias_q[t] = bias[t * 16 + m];

    const int nwaves = (gridDim.x * blockDim.x) >> 6;   // 3072
    const int gw = (blockIdx.x * blockDim.x + threadIdx.x) >> 6;

    for (int rt = gw; rt < NTILES; rt += nwaves) {
        const int rtu = __builtin_amdgcn_readfirstlane(rt);
        const float* xt = x + (size_t)rtu * (16 * FIN);

        // A fragments: frag[j] = x[row = m][k = 32h + quad*8 + j] of the tile.
        bf16x8 af[2];
#pragma unroll
        for (int h = 0; h < 2; ++h) {
            const float4* p4 =
                (const float4*)(xt + (size_t)m * FIN + 32 * h + quad * 8);
            const float4 lo = p4[0];
            const float4 hi = p4[1];
            bf16x8 fr;
            fr[0] = f2b(lo.x); fr[1] = f2b(lo.y);
            fr[2] = f2b(lo.z); fr[3] = f2b(lo.w);
            fr[4] = f2b(hi.x); fr[5] = f2b(hi.y);
            fr[6] = f2b(hi.z); fr[7] = f2b(hi.w);
            af[h] = fr;
        }

        f32x4 acc[8];
#pragma unroll
        for (int t = 0; t < 8; ++t) acc[t] = (f32x4){0.f, 0.f, 0.f, 0.f};
#pragma unroll
        for (int h = 0; h < 2; ++h)
#pragma unroll
            for (int t = 0; t < 8; ++t)
                acc[t] = __builtin_amdgcn_mfma_f32_16x16x32_bf16(
                    af[h], bf[t][h], acc[t], 0, 0, 0);

        // C/D layout (verified m89/m91): value r of tile t sits at
        // row = quad*4 + r, col = (t&3)*16 + m.
        const size_t rbase = (size_t)rtu * 16 + quad * 4;
#pragma unroll
        for (int r = 0; r < 4; ++r) {
            const size_t orow = (rbase + r) * NCOUT;
#pragma unroll
            for (int t = 0; t < 4; ++t)
                out[orow + t * 16 + m] = acc[t][r] + bias_q[t];
#pragma unroll
            for (int t = 4; t < 8; ++t)
                z[orow + (t - 4) * 16 + m] = __float2bfloat16(acc[t][r]);
        }
    }
}

// ---------------------------------------------------------------------------
// Pass B: out[b,v,:] += sum_k z[b, nbr[v,k]-1, :]  (idx==0 = zero pad).
// Pure gather-add: no matmul VALU. bf16 z window/batch = 2.56 MB < 4 MiB L2;
// 1024 blocks @ (256,4) = exactly 4 blocks/CU -> ALL blocks co-resident, and
// blockIdx%8 pins each XCD to its two batches (one live window per L2).
// ---------------------------------------------------------------------------
__global__ __launch_bounds__(256, 4) void convnet_gather(
    const int* __restrict__ nbr,           // (20000, 16), values in [0, V]
    const __hip_bfloat16* __restrict__ z,  // (320000, 64) bf16
    float* __restrict__ out)               // (320000, 64) fp32, has p already
{
    const int lane = threadIdx.x & 63;
    const int xcd  = blockIdx.x & 7;
    const int bi   = blockIdx.x >> 3;                       // 0..127
    const int wl   = (bi * blockDim.x + threadIdx.x) >> 6;  // 0..511
    const int rows_per_xcd = 2 * NV;
    const int base = xcd * rows_per_xcd;

    for (int r = wl; r < rows_per_xcd; r += 512) {
        const int rowu = __builtin_amdgcn_readfirstlane(base + r);
        const int in_b1 = (r >= NV) ? 1 : 0;
        const int v = r - in_b1 * NV;

        const int* nbrow = nbr + (size_t)v * NK;
        const size_t zbase = (size_t)(rowu - v) * NCOUT;    // b*NV*64

        float g0 = 0.f, g1 = 0.f, g2 = 0.f, g3 = 0.f;
#pragma unroll
        for (int k = 0; k < NK; ++k) {
            const int idx = nbrow[k];                       // uniform s_load
            int sel = idx - 1;
            sel = sel < 0 ? 0 : sel;                        // clamp pad
            const float val =
                __bfloat162float(z[zbase + (size_t)sel * NCOUT + lane]);
            const float mval = idx ? val : 0.0f;
            if ((k & 3) == 0) g0 += mval;
            else if ((k & 3) == 1) g1 += mval;
            else if ((k & 3) == 2) g2 += mval;
            else g3 += mval;
        }

        const size_t o = (size_t)rowu * NCOUT + lane;
        out[o] += (g0 + g1) + (g2 + g3);
    }
}

extern "C" void kernel_launch(void* const* d_in, const int* in_sizes, int n_in,
                              void* d_out, int out_size, void* d_ws, size_t ws_size,
                              hipStream_t stream) {
    const float* x    = (const float*)d_in[0];
    const float* Wx   = (const float*)d_in[1];
    const float* Wn   = (const float*)d_in[2];
    const float* bias = (const float*)d_in[3];
    const int*   nbr  = (const int*)d_in[4];
    float* out = (float*)d_out;

    __hip_bfloat16* z = (__hip_bfloat16*)d_ws;   // 40.96 MB (proven fits ws)

    hipLaunchKernelGGL(convnet_gemm, dim3(768), dim3(256), 0, stream,
                       x, Wx, Wn, bias, z, out);
    hipLaunchKernelGGL(convnet_gather, dim3(1024), dim3(256), 0, stream,
                       nbr, z, out);
}